// Round 1
// baseline (660.605 us; speedup 1.0000x reference)
//
#include <hip/hip_runtime.h>

// Local context aggregation (DGCNN edge-conv style), MI355X.
// Pipeline:
//   k_feat : per-point transforms yF1=A1f·x, yFc=(A2f-A1f)·x, yD1=A1d·x, yDc=(A2d-A1d)·x, plus xx=|x|^2
//   k_dist : fp32 tiled score pass (2·x_n·x_m − |x_m|²) + per-lane top-10 + f64 re-rank of top-24 → idx[B,N,20]
//   k_stats: per-channel Σnorm, Σnorm² (double atomics)
//   k_bn   : scale/shift from BN stats
//   k_out  : gather, normalize, directional leaky-ReLU, mean over k
// ws usage ~27 MB.

namespace {
constexpr int BB = 4;
constexpr int NN = 4096;
constexpr int KK = 20;
constexpr int CC = 96;      // 32 features x 3 dims
constexpr int OO = 32;
constexpr int PTS = BB * NN;

constexpr int TM = 128;     // m-tile for distance pass
constexpr int RB = 32;      // rows per block
constexpr int LTOP = 10;    // per-lane top list length
constexpr int TCAND = 24;   // candidates sent to f64 refine
constexpr int RSTRIDE = 100; // padded LDS row stride (floats), 16B-aligned, breaks bank conflicts
}

// ---------------- kernel 1: per-point transforms + |x|^2 ----------------
__global__ __launch_bounds__(256) void k_feat(
    const float* __restrict__ x, const float* __restrict__ Wf,
    const float* __restrict__ Wd,
    float* __restrict__ yF1, float* __restrict__ yFc,
    float* __restrict__ yD1, float* __restrict__ yDc,
    float* __restrict__ xx) {
  __shared__ float sW[4][32][32];     // [A1f, A2f-A1f, A1d, A2d-A1d][f][o]
  __shared__ float sx[8][RSTRIDE];    // 8 points x 96 channels (padded)
  const int t = threadIdx.x;
  for (int i = t; i < 2048; i += 256) {
    int o = i & 31, f = (i >> 5) & 31, which = i >> 10;
    const float* W = which ? Wd : Wf;
    float a1 = W[o * 64 + f], a2 = W[o * 64 + 32 + f];
    sW[which * 2 + 0][f][o] = a1;
    sW[which * 2 + 1][f][o] = a2 - a1;
  }
  const int b = blockIdx.x >> 9;            // 512 blocks per batch
  const int n0 = (blockIdx.x & 511) * 8;
  for (int i = t; i < 8 * CC; i += 256) {
    int pl = i & 7, c = i >> 3;
    sx[pl][c] = x[((size_t)b * CC + c) * NN + n0 + pl];
  }
  __syncthreads();
  const int o = t & 31, pl = t >> 5;
  float aF1[3] = {0.f, 0.f, 0.f}, aFc[3] = {0.f, 0.f, 0.f};
  float aD1[3] = {0.f, 0.f, 0.f}, aDc[3] = {0.f, 0.f, 0.f};
#pragma unroll
  for (int f = 0; f < 32; ++f) {
    float w0 = sW[0][f][o], w1 = sW[1][f][o];
    float w2 = sW[2][f][o], w3 = sW[3][f][o];
#pragma unroll
    for (int dd = 0; dd < 3; ++dd) {
      float v = sx[pl][f * 3 + dd];
      aF1[dd] = fmaf(w0, v, aF1[dd]);
      aFc[dd] = fmaf(w1, v, aFc[dd]);
      aD1[dd] = fmaf(w2, v, aD1[dd]);
      aDc[dd] = fmaf(w3, v, aDc[dd]);
    }
  }
  const size_t pt = (size_t)(b * NN + n0 + pl) * CC + o * 3;
#pragma unroll
  for (int dd = 0; dd < 3; ++dd) {
    yF1[pt + dd] = aF1[dd]; yFc[pt + dd] = aFc[dd];
    yD1[pt + dd] = aD1[dd]; yDc[pt + dd] = aDc[dd];
  }
  float part = 0.f;
#pragma unroll
  for (int dd = 0; dd < 3; ++dd) { float v = sx[pl][o * 3 + dd]; part += v * v; }
#pragma unroll
  for (int off = 16; off >= 1; off >>= 1) part += __shfl_down(part, off, 32);
  if (o == 0) xx[b * NN + n0 + pl] = part;
}

// ---------------- kernel 2: distances + exact top-k ----------------
__global__ __launch_bounds__(256) void k_dist(
    const float* __restrict__ x, const float* __restrict__ xx,
    int* __restrict__ idxout) {
  __shared__ __align__(16) float smem[CC * TM + RB * RSTRIDE + TM];
  float* tile = smem;                       // [96][128] f32 (reused as merge scratch)
  float* rows = smem + CC * TM;             // [32][RSTRIDE]
  float* sxx  = rows + RB * RSTRIDE;        // [128]
  const int t = threadIdx.x;
  const int b = blockIdx.x >> 7;            // 128 blocks per batch
  const int n0 = (blockIdx.x & 127) * RB;
  const float* xb = x + (size_t)b * CC * NN;

  for (int i = t; i < RB * CC; i += 256) {
    int r = i & 31, c = i >> 5;
    rows[r * RSTRIDE + c] = xb[(size_t)c * NN + n0 + r];
  }
  float ls[4][LTOP]; int lid[4][LTOP];
#pragma unroll
  for (int q = 0; q < 4; ++q)
#pragma unroll
    for (int j = 0; j < LTOP; ++j) { ls[q][j] = -3.0e38f; lid[q][j] = 0x7fffffff; }

  const int mr = t & 31, rt = t >> 5;       // 8 row-groups (half-wave) x 32 m-lanes
  float4* tv = (float4*)tile;

  for (int tb = 0; tb < NN / TM; ++tb) {
    __syncthreads();
    const int mstart = tb * TM;
    for (int i = t; i < CC * TM / 4; i += 256) {
      int c = i >> 5, f4 = i & 31;
      tv[c * 32 + f4] = *(const float4*)&xb[(size_t)c * NN + mstart + f4 * 4];
    }
    if (t < TM / 4) ((float4*)sxx)[t] = *(const float4*)&xx[b * NN + mstart + t * 4];
    __syncthreads();

    float acc[4][4];
#pragma unroll
    for (int q = 0; q < 4; ++q)
#pragma unroll
      for (int i2 = 0; i2 < 4; ++i2) acc[q][i2] = 0.f;

    for (int c = 0; c < CC; c += 4) {
      float4 xn[4];
#pragma unroll
      for (int q = 0; q < 4; ++q)
        xn[q] = *(const float4*)&rows[(rt * 4 + q) * RSTRIDE + c];
#pragma unroll
      for (int j = 0; j < 4; ++j) {
        float4 xm = tv[(c + j) * 32 + mr];
#pragma unroll
        for (int q = 0; q < 4; ++q) {
          float xnv = (j == 0) ? xn[q].x : (j == 1) ? xn[q].y : (j == 2) ? xn[q].z : xn[q].w;
          acc[q][0] = fmaf(xnv, xm.x, acc[q][0]);
          acc[q][1] = fmaf(xnv, xm.y, acc[q][1]);
          acc[q][2] = fmaf(xnv, xm.z, acc[q][2]);
          acc[q][3] = fmaf(xnv, xm.w, acc[q][3]);
        }
      }
    }
    const int mb = mstart + mr * 4;
#pragma unroll
    for (int q = 0; q < 4; ++q) {
#pragma unroll
      for (int i2 = 0; i2 < 4; ++i2) {
        float s = 2.f * acc[q][i2] - sxx[mr * 4 + i2];
        if (s > ls[q][LTOP - 1]) {
          ls[q][LTOP - 1] = s; lid[q][LTOP - 1] = mb + i2;
#pragma unroll
          for (int j = LTOP - 1; j > 0; --j) {
            if (ls[q][j] > ls[q][j - 1]) {
              float tsw = ls[q][j]; ls[q][j] = ls[q][j - 1]; ls[q][j - 1] = tsw;
              int tiw = lid[q][j]; lid[q][j] = lid[q][j - 1]; lid[q][j - 1] = tiw;
            }
          }
        }
      }
    }
  }
  __syncthreads();  // tile reads done; reuse tile as merge scratch

  float* ms = tile + rt * (32 * LTOP);
  int* mi = (int*)(tile + 8 * 32 * LTOP) + rt * (32 * LTOP);
  int* cA = (int*)(tile + 16 * 32 * LTOP) + rt * TCAND;

#pragma unroll
  for (int q = 0; q < 4; ++q) {
    const int r = rt * 4 + q;
#pragma unroll
    for (int j = 0; j < LTOP; ++j) { ms[mr * LTOP + j] = ls[q][j]; mi[mr * LTOP + j] = lid[q][j]; }
    // fp32 top-24 across the group's 32x10 candidates (each lane's list is sorted desc)
    int ptr = 0;
    for (int sel = 0; sel < TCAND; ++sel) {
      float cs = (ptr < LTOP) ? ms[mr * LTOP + ptr] : -3.0e38f;
      int ci = (ptr < LTOP) ? mi[mr * LTOP + ptr] : 0x7fffffff;
      float bs = cs; int bi = ci; int bl = mr;
#pragma unroll
      for (int off = 16; off >= 1; off >>= 1) {
        float os = __shfl_down(bs, off, 32);
        int oi = __shfl_down(bi, off, 32);
        int ol = __shfl_down(bl, off, 32);
        if (os > bs || (os == bs && oi < bi)) { bs = os; bi = oi; bl = ol; }
      }
      int wl = __shfl(bl, 0, 32);
      int wi = __shfl(bi, 0, 32);
      if (mr == wl) ptr++;
      if (mr == 0) cA[sel] = wi;
    }
    __builtin_amdgcn_wave_barrier();  // compile-time fence: cA written (lane0) then read (all lanes), same wave
    // exact f64 re-rank of 24 candidates -> matches np(f64) top-20 selection
    const int mym = cA[(mr < TCAND) ? mr : (TCAND - 1)];
    double dotd = 0.0, xm2 = 0.0;
    const float* xr = rows + r * RSTRIDE;
#pragma unroll 4
    for (int c = 0; c < CC; ++c) {
      double xmv = (double)xb[(size_t)c * NN + mym];
      dotd = fma((double)xr[c], xmv, dotd);
      xm2 = fma(xmv, xmv, xm2);
    }
    double cur = (mr < TCAND) ? (2.0 * dotd - xm2) : -1.0e300;
    int curi = (mr < TCAND) ? mym : 0x7fffffff;
    int* orow = idxout + (size_t)(b * NN + n0 + r) * KK;
    for (int sel = 0; sel < KK; ++sel) {
      double ts2 = cur; int ti2 = curi;
#pragma unroll
      for (int off = 16; off >= 1; off >>= 1) {
        double os = __shfl_down(ts2, off, 32);
        int oi = __shfl_down(ti2, off, 32);
        if (os > ts2 || (os == ts2 && oi < ti2)) { ts2 = os; ti2 = oi; }
      }
      int wi = __shfl(ti2, 0, 32);
      if (curi == wi) cur = -1.0e300;   // candidate ids are unique
      if (mr == 0) orow[sel] = wi;
    }
  }
}

// ---------------- kernel 3: BN statistics over edge norms ----------------
__global__ __launch_bounds__(256) void k_stats(
    const float* __restrict__ yF1, const float* __restrict__ yFc,
    const int* __restrict__ idx, double* __restrict__ stats) {
  __shared__ float r1[256], r2[256];
  const int t = threadIdx.x, o = t & 31, nl = t >> 5;
  const int b = blockIdx.x >> 9;
  const int n = (blockIdx.x & 511) * 8 + nl;
  const size_t cb = (size_t)(b * NN + n) * CC + o * 3;
  const float pc0 = yFc[cb], pc1 = yFc[cb + 1], pc2 = yFc[cb + 2];
  const int* ip = idx + (size_t)(b * NN + n) * KK;
  float s1 = 0.f, s2 = 0.f;
  for (int k = 0; k < KK; ++k) {
    int m = ip[k];
    size_t a = (size_t)(b * NN + m) * CC + o * 3;
    float p0 = yF1[a] + pc0, p1 = yF1[a + 1] + pc1, p2 = yF1[a + 2] + pc2;
    float nr = sqrtf(p0 * p0 + p1 * p1 + p2 * p2) + 1e-6f;
    s1 += nr; s2 = fmaf(nr, nr, s2);
  }
  r1[t] = s1; r2[t] = s2; __syncthreads();
  if (t < 128) { r1[t] += r1[t + 128]; r2[t] += r2[t + 128]; } __syncthreads();
  if (t < 64) { r1[t] += r1[t + 64]; r2[t] += r2[t + 64]; } __syncthreads();
  if (t < 32) {
    float a1 = r1[t] + r1[t + 32];
    float a2 = r2[t] + r2[t + 32];
    atomicAdd(&stats[t], (double)a1);
    atomicAdd(&stats[32 + t], (double)a2);
  }
}

// ---------------- kernel 4: BN scale/shift ----------------
__global__ void k_bn(const double* __restrict__ stats, const float* __restrict__ gamma,
                     const float* __restrict__ beta, float* __restrict__ ss) {
  int o = threadIdx.x;
  if (o >= 32) return;
  const double M = (double)BB * NN * KK;
  double mean = stats[o] / M;
  double var = stats[32 + o] / M - mean * mean;
  double inv = 1.0 / sqrt(var + 1e-5);
  ss[o] = (float)((double)gamma[o] * inv);
  ss[32 + o] = (float)((double)beta[o] - mean * (double)gamma[o] * inv);
}

// ---------------- kernel 5: gather + activation + mean over k ----------------
__global__ __launch_bounds__(256) void k_out(
    const float* __restrict__ yF1, const float* __restrict__ yFc,
    const float* __restrict__ yD1, const float* __restrict__ yDc,
    const int* __restrict__ idx, const float* __restrict__ ss,
    float* __restrict__ out) {
  const int t = threadIdx.x, o = t & 31, nl = t >> 5;
  const int b = blockIdx.x >> 9;
  const int n = (blockIdx.x & 511) * 8 + nl;
  const size_t cb = (size_t)(b * NN + n) * CC + o * 3;
  const float pc0 = yFc[cb], pc1 = yFc[cb + 1], pc2 = yFc[cb + 2];
  const float dc0 = yDc[cb], dc1 = yDc[cb + 1], dc2 = yDc[cb + 2];
  const float sc = ss[o], sh = ss[32 + o];
  const int* ip = idx + (size_t)(b * NN + n) * KK;
  float a0 = 0.f, a1 = 0.f, a2 = 0.f;
  for (int k = 0; k < KK; ++k) {
    int m = ip[k];
    size_t a = (size_t)(b * NN + m) * CC + o * 3;
    float p0 = yF1[a] + pc0, p1 = yF1[a + 1] + pc1, p2 = yF1[a + 2] + pc2;
    float d0 = yD1[a] + dc0, d1 = yD1[a + 1] + dc1, d2 = yD1[a + 2] + dc2;
    float nr = sqrtf(p0 * p0 + p1 * p1 + p2 * p2) + 1e-6f;
    float f = (sc * nr + sh) / nr;
    p0 *= f; p1 *= f; p2 *= f;
    float dt = p0 * d0 + p1 * d1 + p2 * d2;
    // act = 0.2*p + 0.8*(dot>=0 ? p : p - dot/(dsq+eps)*d)  ==  p - 0.8*[dot<0]*(dot/(dsq+eps))*d
    float w8 = (dt >= 0.f) ? 0.f : 0.8f * dt / (d0 * d0 + d1 * d1 + d2 * d2 + 1e-6f);
    a0 += p0 - w8 * d0; a1 += p1 - w8 * d1; a2 += p2 - w8 * d2;
  }
  const float inv = 1.f / (float)KK;
  const size_t ob = ((size_t)(b * OO + o) * 3) * NN + n;
  out[ob] = a0 * inv; out[ob + NN] = a1 * inv; out[ob + 2 * NN] = a2 * inv;
}

extern "C" void kernel_launch(void* const* d_in, const int* in_sizes, int n_in,
                              void* d_out, int out_size, void* d_ws, size_t ws_size,
                              hipStream_t stream) {
  (void)in_sizes; (void)n_in; (void)out_size;
  const float* x = (const float*)d_in[0];
  const float* Wf = (const float*)d_in[1];
  const float* Wd = (const float*)d_in[2];
  const float* gamma = (const float*)d_in[3];
  const float* beta = (const float*)d_in[4];
  float* out = (float*)d_out;

  char* ws = (char*)d_ws;
  size_t off = 0;
  auto alloc = [&](size_t bytes) -> void* {
    void* p = ws + off;
    off += (bytes + 255) & ~(size_t)255;
    return p;
  };
  float* yF1 = (float*)alloc((size_t)PTS * CC * 4);
  float* yFc = (float*)alloc((size_t)PTS * CC * 4);
  float* yD1 = (float*)alloc((size_t)PTS * CC * 4);
  float* yDc = (float*)alloc((size_t)PTS * CC * 4);
  float* xx  = (float*)alloc((size_t)PTS * 4);
  int* idx   = (int*)alloc((size_t)PTS * KK * 4);
  double* stats = (double*)alloc(64 * 8);
  float* ss  = (float*)alloc(64 * 4);
  if (ws_size < off) return;  // fail loudly rather than corrupt

  hipMemsetAsync(stats, 0, 64 * 8, stream);
  k_feat<<<dim3(PTS / 8), dim3(256), 0, stream>>>(x, Wf, Wd, yF1, yFc, yD1, yDc, xx);
  k_dist<<<dim3(BB * (NN / RB)), dim3(256), 0, stream>>>(x, xx, idx);
  k_stats<<<dim3(PTS / 8), dim3(256), 0, stream>>>(yF1, yFc, idx, stats);
  k_bn<<<dim3(1), dim3(64), 0, stream>>>(stats, gamma, beta, ss);
  k_out<<<dim3(PTS / 8), dim3(256), 0, stream>>>(yF1, yFc, yD1, yDc, idx, ss, out);
}

// Round 3
// 516.838 us; speedup vs baseline: 1.2782x; 1.2782x over previous
//
#include <hip/hip_runtime.h>

// Local context aggregation (DGCNN edge-conv style), MI355X.
// Pipeline:
//   k_feat : per-point transforms yF1=A1f·x, yFc=(A2f-A1f)·x, yD1, yDc + xx=|x|^2
//   k_prep : split-bf16 tables hl[n][hi96|lo96] + transposed xT[n][96] f32
//   k_gemm : LDS-free MFMA split-bf16 Gram GEMM -> scores (dot - 0.5*xx[m]) to HBM chunk
//            (per-batch table is 1.57 MB -> L2-resident; fragments loaded straight from global)
//   k_topk : per-row scan top-8/lane -> 64-lane shfl merge top-24 -> exact f64 re-rank -> idx[20]
//   k_stats/k_bn/k_out : BN over edge norms + directional leaky act + mean over k
// ws usage: ~39 MB fixed + adaptive score chunk.

namespace {
constexpr int BB = 4;
constexpr int NN = 4096;
constexpr int KK = 20;
constexpr int CC = 96;      // 32 features x 3 dims
constexpr int OO = 32;
constexpr int PTS = BB * NN;
constexpr int LTOP = 8;     // per-lane top list (64 lanes/row)
constexpr int TCAND = 24;   // candidates sent to f64 refine
constexpr int RSTRIDE = 100;
}

using bf16x8 = __attribute__((ext_vector_type(8))) short;
using f32x4 = __attribute__((ext_vector_type(4))) float;

__device__ __forceinline__ unsigned short f2bf(float f) {
  unsigned u = __float_as_uint(f);
  return (unsigned short)((u + 0x7fff + ((u >> 16) & 1)) >> 16);
}
__device__ __forceinline__ float bf2f(unsigned short b) {
  return __uint_as_float((unsigned)b << 16);
}

// ---------------- kernel 1: per-point transforms + |x|^2 ----------------
__global__ __launch_bounds__(256) void k_feat(
    const float* __restrict__ x, const float* __restrict__ Wf,
    const float* __restrict__ Wd,
    float* __restrict__ yF1, float* __restrict__ yFc,
    float* __restrict__ yD1, float* __restrict__ yDc,
    float* __restrict__ xx) {
  __shared__ float sW[4][32][32];
  __shared__ float sx[8][RSTRIDE];
  const int t = threadIdx.x;
  for (int i = t; i < 2048; i += 256) {
    int o = i & 31, f = (i >> 5) & 31, which = i >> 10;
    const float* W = which ? Wd : Wf;
    float a1 = W[o * 64 + f], a2 = W[o * 64 + 32 + f];
    sW[which * 2 + 0][f][o] = a1;
    sW[which * 2 + 1][f][o] = a2 - a1;
  }
  const int b = blockIdx.x >> 9;
  const int n0 = (blockIdx.x & 511) * 8;
  for (int i = t; i < 8 * CC; i += 256) {
    int pl = i & 7, c = i >> 3;
    sx[pl][c] = x[((size_t)b * CC + c) * NN + n0 + pl];
  }
  __syncthreads();
  const int o = t & 31, pl = t >> 5;
  float aF1[3] = {0.f, 0.f, 0.f}, aFc[3] = {0.f, 0.f, 0.f};
  float aD1[3] = {0.f, 0.f, 0.f}, aDc[3] = {0.f, 0.f, 0.f};
#pragma unroll
  for (int f = 0; f < 32; ++f) {
    float w0 = sW[0][f][o], w1 = sW[1][f][o];
    float w2 = sW[2][f][o], w3 = sW[3][f][o];
#pragma unroll
    for (int dd = 0; dd < 3; ++dd) {
      float v = sx[pl][f * 3 + dd];
      aF1[dd] = fmaf(w0, v, aF1[dd]);
      aFc[dd] = fmaf(w1, v, aFc[dd]);
      aD1[dd] = fmaf(w2, v, aD1[dd]);
      aDc[dd] = fmaf(w3, v, aDc[dd]);
    }
  }
  const size_t pt = (size_t)(b * NN + n0 + pl) * CC + o * 3;
#pragma unroll
  for (int dd = 0; dd < 3; ++dd) {
    yF1[pt + dd] = aF1[dd]; yFc[pt + dd] = aFc[dd];
    yD1[pt + dd] = aD1[dd]; yDc[pt + dd] = aDc[dd];
  }
  float part = 0.f;
#pragma unroll
  for (int dd = 0; dd < 3; ++dd) { float v = sx[pl][o * 3 + dd]; part += v * v; }
#pragma unroll
  for (int off = 16; off >= 1; off >>= 1) part += __shfl_down(part, off, 32);
  if (o == 0) xx[b * NN + n0 + pl] = part;
}

// ---------------- kernel 1b: split-bf16 + transposed tables ----------------
__global__ __launch_bounds__(256) void k_prep(
    const float* __restrict__ x, unsigned short* __restrict__ hl,
    float* __restrict__ xT) {
  __shared__ float tile[CC][65];
  const int t = threadIdx.x;
  const int b = blockIdx.x >> 6;             // 64 blocks per batch
  const int n0 = (blockIdx.x & 63) * 64;
#pragma unroll
  for (int i = 0; i < 24; ++i) {
    int v = i * 256 + t;
    int c = v >> 6, nn = v & 63;
    tile[c][nn] = x[((size_t)b * CC + c) * NN + n0 + nn];
  }
  __syncthreads();
  // hl rows: [hi 96 | lo 96] bf16, written as 24 x 16B chunks per row
#pragma unroll
  for (int i = 0; i < 6; ++i) {
    int v = i * 256 + t;                    // 0..1535 over 64 rows x 24 chunks
    int row = v / 24, k8 = v % 24;
    unsigned hb[4];
    if (k8 < 12) {
      int c0 = k8 * 8;
#pragma unroll
      for (int j = 0; j < 4; ++j) {
        unsigned short l16 = f2bf(tile[c0 + 2 * j][row]);
        unsigned short h16 = f2bf(tile[c0 + 2 * j + 1][row]);
        hb[j] = (unsigned)l16 | ((unsigned)h16 << 16);
      }
    } else {
      int c0 = (k8 - 12) * 8;
#pragma unroll
      for (int j = 0; j < 4; ++j) {
        float f0 = tile[c0 + 2 * j][row], f1 = tile[c0 + 2 * j + 1][row];
        unsigned short h0 = f2bf(f0), h1 = f2bf(f1);
        unsigned short l0 = f2bf(f0 - bf2f(h0)), l1 = f2bf(f1 - bf2f(h1));
        hb[j] = (unsigned)l0 | ((unsigned)l1 << 16);
      }
    }
    *(uint4*)(hl + (size_t)(b * NN + n0 + row) * 192 + k8 * 8) =
        make_uint4(hb[0], hb[1], hb[2], hb[3]);
  }
  // xT rows: 96 f32 contiguous per point
#pragma unroll
  for (int i = 0; i < 6; ++i) {
    int v = i * 256 + t;
    int row = v / 24, q = v % 24;
    float4 o4;
    o4.x = tile[q * 4 + 0][row]; o4.y = tile[q * 4 + 1][row];
    o4.z = tile[q * 4 + 2][row]; o4.w = tile[q * 4 + 3][row];
    *(float4*)(xT + (size_t)(b * NN + n0 + row) * CC + q * 4) = o4;
  }
}

// ---------------- kernel 2a: LDS-free MFMA split-bf16 score GEMM ----------------
// Per block: 128 n-rows (4 waves x 32) x 64 m-cols. Fragments straight from L2.
__global__ __launch_bounds__(256) void k_gemm(
    const unsigned short* __restrict__ hl, const float* __restrict__ xx,
    float* __restrict__ Sc, int b, int r0) {
  const int t = threadIdx.x, lane = t & 63, w = t >> 6;
  const int m_base = blockIdx.x * 64;
  const int n_wave = r0 + blockIdx.y * 128 + w * 32;   // within batch
  const unsigned short* hb = hl + (size_t)b * NN * 192;
  const int kl = lane >> 4;       // k-group 0..3
  const int pr = lane & 15;       // point-in-fragment

  f32x4 acc[2][4];
#pragma unroll
  for (int sm = 0; sm < 4; ++sm) {
    float xv = -0.5f * xx[b * NN + m_base + sm * 16 + pr];
#pragma unroll
    for (int sn = 0; sn < 2; ++sn) acc[sn][sm] = {xv, xv, xv, xv};
  }
#pragma unroll
  for (int kb = 0; kb < 3; ++kb) {
    bf16x8 aH[2], aL[2], bH[4], bL[4];
#pragma unroll
    for (int sn = 0; sn < 2; ++sn) {
      const unsigned short* p = hb + (size_t)(n_wave + sn * 16 + pr) * 192 + (kb * 4 + kl) * 8;
      aH[sn] = *(const bf16x8*)p;
      aL[sn] = *(const bf16x8*)(p + 96);
    }
#pragma unroll
    for (int sm = 0; sm < 4; ++sm) {
      const unsigned short* p = hb + (size_t)(m_base + sm * 16 + pr) * 192 + (kb * 4 + kl) * 8;
      bH[sm] = *(const bf16x8*)p;
      bL[sm] = *(const bf16x8*)(p + 96);
    }
    // (hiA+loA)·(hiB+loB) ~= hi·hi + lo·hi + hi·lo (lo·lo ~2^-16, below rank gap)
#pragma unroll
    for (int sn = 0; sn < 2; ++sn)
#pragma unroll
      for (int sm = 0; sm < 4; ++sm) {
        acc[sn][sm] = __builtin_amdgcn_mfma_f32_16x16x32_bf16(aH[sn], bH[sm], acc[sn][sm], 0, 0, 0);
        acc[sn][sm] = __builtin_amdgcn_mfma_f32_16x16x32_bf16(aL[sn], bH[sm], acc[sn][sm], 0, 0, 0);
        acc[sn][sm] = __builtin_amdgcn_mfma_f32_16x16x32_bf16(aH[sn], bL[sm], acc[sn][sm], 0, 0, 0);
      }
  }
  // C/D layout: col = lane&15 (m), row = (lane>>4)*4 + reg (n)  [m89-verified]
  const int n_loc_base = blockIdx.y * 128 + w * 32;
#pragma unroll
  for (int sn = 0; sn < 2; ++sn)
#pragma unroll
    for (int sm = 0; sm < 4; ++sm) {
      int m = m_base + sm * 16 + pr;
#pragma unroll
      for (int r = 0; r < 4; ++r) {
        int n_loc = n_loc_base + sn * 16 + kl * 4 + r;
        Sc[(size_t)n_loc * NN + m] = acc[sn][sm][r];
      }
    }
}

// ---------------- kernel 2b: per-row top-k from score matrix (no LDS) ----------------
__global__ __launch_bounds__(256) void k_topk(
    const float* __restrict__ Sc, const float* __restrict__ xT,
    int* __restrict__ idxout, int b, int r0) {
  const int t = threadIdx.x, lane = t & 63, w = t >> 6;
  const int n_loc = blockIdx.x * 4 + w;      // row within chunk
  const int n = r0 + n_loc;                  // within batch
  const float* row = Sc + (size_t)n_loc * NN;
  float ls[LTOP]; int lid[LTOP];
#pragma unroll
  for (int j = 0; j < LTOP; ++j) { ls[j] = -3.0e38f; lid[j] = 0x7fffffff; }
#pragma unroll 4
  for (int j = 0; j < 16; ++j) {
    int idx4 = j * 64 + lane;
    float4 v = *(const float4*)&row[idx4 * 4];
#pragma unroll
    for (int e = 0; e < 4; ++e) {
      float s = (e == 0) ? v.x : (e == 1) ? v.y : (e == 2) ? v.z : v.w;
      if (s > ls[LTOP - 1]) {
        ls[LTOP - 1] = s; lid[LTOP - 1] = idx4 * 4 + e;
#pragma unroll
        for (int q = LTOP - 1; q > 0; --q) {
          if (ls[q] > ls[q - 1]) {
            float tf = ls[q]; ls[q] = ls[q - 1]; ls[q - 1] = tf;
            int ti = lid[q]; lid[q] = lid[q - 1]; lid[q - 1] = ti;
          }
        }
      }
    }
  }
  // 64-lane merge -> lane 'sel' keeps candidate sel (fp32 ordering); pure shfl
  int mycand = 0;
  int ptr = 0;
  for (int sel = 0; sel < TCAND; ++sel) {
    float bs = (ptr < LTOP) ? ls[ptr] : -3.0e38f;
    int bi = (ptr < LTOP) ? lid[ptr] : 0x7fffffff;
    int bl = lane;
#pragma unroll
    for (int off = 32; off >= 1; off >>= 1) {
      float os = __shfl_down(bs, off);
      int oi = __shfl_down(bi, off);
      int ol = __shfl_down(bl, off);
      if (os > bs || (os == bs && oi < bi)) { bs = os; bi = oi; bl = ol; }
    }
    int wl = __shfl(bl, 0);
    int wi = __shfl(bi, 0);
    if (lane == wl) ptr++;
    if (lane == sel) mycand = wi;
  }
  // exact f64 re-rank of the 24 candidates (matches np f64 top_k; ties -> lower index)
  const float* xm = xT + ((size_t)b * NN + mycand) * CC;
  const float* xr = xT + ((size_t)b * NN + n) * CC;
  double dot = 0.0, m2 = 0.0;
#pragma unroll 4
  for (int j = 0; j < 24; ++j) {
    float4 a = *(const float4*)&xm[j * 4];
    float4 rr = *(const float4*)&xr[j * 4];
    dot = fma((double)rr.x, (double)a.x, dot); m2 = fma((double)a.x, (double)a.x, m2);
    dot = fma((double)rr.y, (double)a.y, dot); m2 = fma((double)a.y, (double)a.y, m2);
    dot = fma((double)rr.z, (double)a.z, dot); m2 = fma((double)a.z, (double)a.z, m2);
    dot = fma((double)rr.w, (double)a.w, dot); m2 = fma((double)a.w, (double)a.w, m2);
  }
  double cur = (lane < TCAND) ? (2.0 * dot - m2) : -1.0e300;
  int curi = (lane < TCAND) ? mycand : 0x7fffffff;
  int* orow = idxout + ((size_t)b * NN + n) * KK;
  for (int sel = 0; sel < KK; ++sel) {
    double ts2 = cur; int ti2 = curi;
#pragma unroll
    for (int off = 32; off >= 1; off >>= 1) {
      double os = __shfl_down(ts2, off);
      int oi = __shfl_down(ti2, off);
      if (os > ts2 || (os == ts2 && oi < ti2)) { ts2 = os; ti2 = oi; }
    }
    int wi = __shfl(ti2, 0);
    if (curi == wi) cur = -1.0e300;   // candidate ids are unique across lanes
    if (lane == 0) orow[sel] = wi;
  }
}

// ---------------- kernel 3: BN statistics over edge norms ----------------
__global__ __launch_bounds__(256) void k_stats(
    const float* __restrict__ yF1, const float* __restrict__ yFc,
    const int* __restrict__ idx, double* __restrict__ stats) {
  __shared__ float r1[256], r2[256];
  const int t = threadIdx.x, o = t & 31, nl = t >> 5;
  const int b = blockIdx.x >> 9;
  const int n = (blockIdx.x & 511) * 8 + nl;
  const size_t cb = (size_t)(b * NN + n) * CC + o * 3;
  const float pc0 = yFc[cb], pc1 = yFc[cb + 1], pc2 = yFc[cb + 2];
  const int* ip = idx + (size_t)(b * NN + n) * KK;
  float s1 = 0.f, s2 = 0.f;
  for (int k = 0; k < KK; ++k) {
    int m = ip[k];
    size_t a = (size_t)(b * NN + m) * CC + o * 3;
    float p0 = yF1[a] + pc0, p1 = yF1[a + 1] + pc1, p2 = yF1[a + 2] + pc2;
    float nr = sqrtf(p0 * p0 + p1 * p1 + p2 * p2) + 1e-6f;
    s1 += nr; s2 = fmaf(nr, nr, s2);
  }
  r1[t] = s1; r2[t] = s2; __syncthreads();
  if (t < 128) { r1[t] += r1[t + 128]; r2[t] += r2[t + 128]; } __syncthreads();
  if (t < 64) { r1[t] += r1[t + 64]; r2[t] += r2[t + 64]; } __syncthreads();
  if (t < 32) {
    float a1 = r1[t] + r1[t + 32];
    float a2 = r2[t] + r2[t + 32];
    atomicAdd(&stats[t], (double)a1);
    atomicAdd(&stats[32 + t], (double)a2);
  }
}

// ---------------- kernel 4: BN scale/shift ----------------
__global__ void k_bn(const double* __restrict__ stats, const float* __restrict__ gamma,
                     const float* __restrict__ beta, float* __restrict__ ss) {
  int o = threadIdx.x;
  if (o >= 32) return;
  const double M = (double)BB * NN * KK;
  double mean = stats[o] / M;
  double var = stats[32 + o] / M - mean * mean;
  double inv = 1.0 / sqrt(var + 1e-5);
  ss[o] = (float)((double)gamma[o] * inv);
  ss[32 + o] = (float)((double)beta[o] - mean * (double)gamma[o] * inv);
}

// ---------------- kernel 5: gather + activation + mean over k ----------------
__global__ __launch_bounds__(256) void k_out(
    const float* __restrict__ yF1, const float* __restrict__ yFc,
    const float* __restrict__ yD1, const float* __restrict__ yDc,
    const int* __restrict__ idx, const float* __restrict__ ss,
    float* __restrict__ out) {
  const int t = threadIdx.x, o = t & 31, nl = t >> 5;
  const int b = blockIdx.x >> 9;
  const int n = (blockIdx.x & 511) * 8 + nl;
  const size_t cb = (size_t)(b * NN + n) * CC + o * 3;
  const float pc0 = yFc[cb], pc1 = yFc[cb + 1], pc2 = yFc[cb + 2];
  const float dc0 = yDc[cb], dc1 = yDc[cb + 1], dc2 = yDc[cb + 2];
  const float sc = ss[o], sh = ss[32 + o];
  const int* ip = idx + (size_t)(b * NN + n) * KK;
  float a0 = 0.f, a1 = 0.f, a2 = 0.f;
  for (int k = 0; k < KK; ++k) {
    int m = ip[k];
    size_t a = (size_t)(b * NN + m) * CC + o * 3;
    float p0 = yF1[a] + pc0, p1 = yF1[a + 1] + pc1, p2 = yF1[a + 2] + pc2;
    float d0 = yD1[a] + dc0, d1 = yD1[a + 1] + dc1, d2 = yD1[a + 2] + dc2;
    float nr = sqrtf(p0 * p0 + p1 * p1 + p2 * p2) + 1e-6f;
    float f = (sc * nr + sh) / nr;
    p0 *= f; p1 *= f; p2 *= f;
    float dt = p0 * d0 + p1 * d1 + p2 * d2;
    float w8 = (dt >= 0.f) ? 0.f : 0.8f * dt / (d0 * d0 + d1 * d1 + d2 * d2 + 1e-6f);
    a0 += p0 - w8 * d0; a1 += p1 - w8 * d1; a2 += p2 - w8 * d2;
  }
  const float inv = 1.f / (float)KK;
  const size_t ob = ((size_t)(b * OO + o) * 3) * NN + n;
  out[ob] = a0 * inv; out[ob + NN] = a1 * inv; out[ob + 2 * NN] = a2 * inv;
}

extern "C" void kernel_launch(void* const* d_in, const int* in_sizes, int n_in,
                              void* d_out, int out_size, void* d_ws, size_t ws_size,
                              hipStream_t stream) {
  (void)in_sizes; (void)n_in; (void)out_size;
  const float* x = (const float*)d_in[0];
  const float* Wf = (const float*)d_in[1];
  const float* Wd = (const float*)d_in[2];
  const float* gamma = (const float*)d_in[3];
  const float* beta = (const float*)d_in[4];
  float* out = (float*)d_out;

  char* ws = (char*)d_ws;
  size_t off = 0;
  auto alloc = [&](size_t bytes) -> void* {
    void* p = ws + off;
    off += (bytes + 255) & ~(size_t)255;
    return p;
  };
  float* yF1 = (float*)alloc((size_t)PTS * CC * 4);
  float* yFc = (float*)alloc((size_t)PTS * CC * 4);
  float* yD1 = (float*)alloc((size_t)PTS * CC * 4);
  float* yDc = (float*)alloc((size_t)PTS * CC * 4);
  float* xx  = (float*)alloc((size_t)PTS * 4);
  int* idx   = (int*)alloc((size_t)PTS * KK * 4);
  double* stats = (double*)alloc(64 * 8);
  float* ss  = (float*)alloc(64 * 4);
  unsigned short* hl = (unsigned short*)alloc((size_t)PTS * 192 * 2);
  float* xT  = (float*)alloc((size_t)PTS * CC * 4);
  if (ws_size < off + (size_t)128 * NN * 4) return;  // need at least a 128-row score chunk

  size_t leftover = ws_size - off;
  int R = (int)(leftover / ((size_t)NN * 4));
  R = (R / 128) * 128;
  if (R > NN) R = NN;
  float* Scb = (float*)alloc((size_t)R * NN * 4);

  hipMemsetAsync(stats, 0, 64 * 8, stream);
  k_feat<<<dim3(PTS / 8), dim3(256), 0, stream>>>(x, Wf, Wd, yF1, yFc, yD1, yDc, xx);
  k_prep<<<dim3(PTS / 64), dim3(256), 0, stream>>>(x, hl, xT);
  for (int b = 0; b < BB; ++b) {
    for (int r0 = 0; r0 < NN; r0 += R) {
      int Rc = (NN - r0 < R) ? (NN - r0) : R;
      k_gemm<<<dim3(NN / 64, Rc / 128), dim3(256), 0, stream>>>(hl, xx, Scb, b, r0);
      k_topk<<<dim3(Rc / 4), dim3(256), 0, stream>>>(Scb, xT, idx, b, r0);
    }
  }
  k_stats<<<dim3(PTS / 8), dim3(256), 0, stream>>>(yF1, yFc, idx, stats);
  k_bn<<<dim3(1), dim3(64), 0, stream>>>(stats, gamma, beta, ss);
  k_out<<<dim3(PTS / 8), dim3(256), 0, stream>>>(yF1, yFc, yD1, yDc, idx, ss, out);
}